// Round 2
// 213.692 us; speedup vs baseline: 1.1092x; 1.1092x over previous
//
#include <hip/hip_runtime.h>
#include <cstdint>

// Problem constants (fixed by the reference).
#define B_   16
#define C_   306
#define T_   4096
#define M_   270
#define G_   64     // 8x8 grid, strides {8,1}
#define MT_  17     // m-tiles of 16 (M padded to 272)
#define KB_  10     // k-blocks of 32 (C=306 padded to 320)
#define TT   64     // t per block
#define BDIM 256
#define NW   4

typedef __attribute__((ext_vector_type(8))) short s8;   // 8 bf16 (4 VGPRs) MFMA frag
typedef __attribute__((ext_vector_type(4))) float f4;   // 4 fp32 accumulator
typedef __attribute__((ext_vector_type(4))) int   i4;

// fp32 -> bf16 (RNE) as raw bits; and back.
__device__ __forceinline__ short f2bf(float f) {
    unsigned u = __builtin_bit_cast(unsigned, f);
    u += 0x7FFFu + ((u >> 16) & 1u);
    return (short)(u >> 16);
}
__device__ __forceinline__ float bf2f(short h) {
    return __builtin_bit_cast(float, ((unsigned)(unsigned short)h) << 16);
}

// ---------------------------------------------------------------------------
// A_build: A[b][m][c] = sum_{4 corners} w_k(b,c) * W[m, g_k(b,c)]  (dense fold
// of the scatter matrix into grid_weights: out = (W@S_b) @ x).
// One block per (mt, b). Emits MFMA A-fragments split hi/lo bf16:
//   record (mt,kb,lane): A[m = mt*16 + (lane&15)][k = kb*32 + (lane>>4)*8 + j]
// ---------------------------------------------------------------------------
__global__ __launch_bounds__(BDIM) void a_build(const float* __restrict__ pos,
                                                const float* __restrict__ gw,
                                                i4* __restrict__ Ah,
                                                i4* __restrict__ Al) {
    __shared__ float At[16][321];   // k padded to 320; stride 321 -> conflict-free
    const int mt  = blockIdx.x;     // 0..16
    const int b   = blockIdx.y;
    const int tid = threadIdx.x;
    const int mr  = tid & 15;       // m within tile
    const int cg  = tid >> 4;       // c group (16 threads share a c)
    const int m   = mt * 16 + mr;

    for (int c = cg; c < KB_ * 32; c += 16) {
        float v = 0.0f;
        if (c < C_ && m < M_) {
            const float* pp = pos + ((size_t)b * C_ + c) * 2;
            float gp0 = (pp[0] + 1.0f) * 4.0f;
            float gp1 = (pp[1] + 1.0f) * 4.0f;
            float f0 = floorf(gp0), f1 = floorf(gp1);
            int l0 = (int)f0, l1 = (int)f1;
            int h0 = (int)ceilf(gp0), h1 = (int)ceilf(gp1);
            float wh0 = gp0 - f0, wh1 = gp1 - f1;
            float wl0 = 1.0f - wh0, wl1 = 1.0f - wh1;
            const float* wm = gw + (size_t)m * G_;
            v = wl0 * wl1 * wm[l0 * 8 + l1] + wl0 * wh1 * wm[l0 * 8 + h1]
              + wh0 * wl1 * wm[h0 * 8 + l1] + wh0 * wh1 * wm[h0 * 8 + h1];
        }
        At[mr][c] = v;
    }
    __syncthreads();

    const int lane = tid & 63;
    const int mr2  = lane & 15;
    const int j0   = (lane >> 4) * 8;
    for (int kb = tid >> 6; kb < KB_; kb += 4) {
        s8 hv, lv;
        #pragma unroll
        for (int j = 0; j < 8; ++j) {
            float v = At[mr2][kb * 32 + j0 + j];
            short h = f2bf(v);
            hv[j] = h;
            lv[j] = f2bf(v - bf2f(h));
        }
        const int idx = ((b * MT_ + mt) * KB_ + kb) * 64 + lane;
        Ah[idx] = __builtin_bit_cast(i4, hv);
        Al[idx] = __builtin_bit_cast(i4, lv);
    }
}

// ---------------------------------------------------------------------------
// GEMM: out[b] = A_b (272x320) @ x[b] (320x64-tile), bf16x3 MFMA, fp32 accum.
// One block per (b, 64-wide t tile), 4 waves. x k-blocks staged through
// double-buffered LDS as transposed bf16 hi/lo [n=64][k=32] (row stride 40
// shorts = 80 B -> 2-way bank aliasing, free). B-frag = one ds_read_b128.
// ---------------------------------------------------------------------------
__global__ __launch_bounds__(BDIM, 3) void gemm_kernel(
    const float* __restrict__ x, const i4* __restrict__ Ahp,
    const i4* __restrict__ Alp, float* __restrict__ out) {
    __shared__ s8 BhT[2][320];   // [buf][row*5 + j8], row = t within tile
    __shared__ s8 BlT[2][320];   // 20.5 KB total

    const int b    = blockIdx.y;
    const int t0   = blockIdx.x * TT;
    const int tid  = threadIdx.x;
    const int lane = tid & 63;
    const int wave = __builtin_amdgcn_readfirstlane(tid >> 6);
    const int quad = lane >> 4;
    const int lcol = lane & 15;
    const int col  = tid & 63;        // t offset this thread stages
    const int rp   = (tid >> 6) * 2;  // even row-pair base: waves own {0,2,4,6}+8i

    const float* xrow = x + (size_t)b * C_ * T_ + t0 + col;

    float r0[4], r1[4];
    // ---- prologue: stage k-block 0 into buffer 0 ----
    #pragma unroll
    for (int i = 0; i < 4; ++i) {
        const int c0 = rp + 8 * i;                 // < 32, always valid
        r0[i] = xrow[(size_t)c0 * T_];
        r1[i] = xrow[(size_t)(c0 + 1) * T_];
    }
    {
        unsigned* wh = (unsigned*)&BhT[0][0];
        unsigned* wl = (unsigned*)&BlT[0][0];
        #pragma unroll
        for (int i = 0; i < 4; ++i) {
            short h0 = f2bf(r0[i]), h1 = f2bf(r1[i]);
            short l0 = f2bf(r0[i] - bf2f(h0)), l1 = f2bf(r1[i] - bf2f(h1));
            wh[col * 20 + (rp >> 1) + 4 * i] =
                (unsigned)(unsigned short)h0 | ((unsigned)(unsigned short)h1 << 16);
            wl[col * 20 + (rp >> 1) + 4 * i] =
                (unsigned)(unsigned short)l0 | ((unsigned)(unsigned short)l1 << 16);
        }
    }
    __syncthreads();

    f4 acc[5][4];
    #pragma unroll
    for (int mi = 0; mi < 5; ++mi)
        #pragma unroll
        for (int nt = 0; nt < 4; ++nt)
            acc[mi][nt] = (f4){0.f, 0.f, 0.f, 0.f};

    int cur = 0;
    for (int kb = 0; kb < KB_; ++kb) {
        const int  nxt = cur ^ 1;
        const bool pf  = (kb + 1 < KB_);

        // issue next k-block's global loads early (T14: latency hides under MFMA)
        if (pf) {
            #pragma unroll
            for (int i = 0; i < 4; ++i) {
                const int c0 = (kb + 1) * 32 + rp + 8 * i;
                r0[i] = (c0 < C_)     ? xrow[(size_t)c0 * T_]       : 0.0f;
                r1[i] = (c0 + 1 < C_) ? xrow[(size_t)(c0 + 1) * T_] : 0.0f;
            }
        }

        // B fragments for this k-block (one ds_read_b128 each)
        s8 bh[4], bl[4];
        #pragma unroll
        for (int nt = 0; nt < 4; ++nt) {
            bh[nt] = BhT[cur][(nt * 16 + lcol) * 5 + quad];
            bl[nt] = BlT[cur][(nt * 16 + lcol) * 5 + quad];
        }

        // A fragments (coalesced dwordx4, L2-hot) + bf16x3 MFMAs
        #pragma unroll
        for (int mi = 0; mi < 5; ++mi) {
            const int mt = wave + mi * NW;
            if (mt < MT_) {                       // wave-uniform branch
                const int idx = ((b * MT_ + mt) * KB_ + kb) * 64 + lane;
                const s8 ah = __builtin_bit_cast(s8, Ahp[idx]);
                const s8 al = __builtin_bit_cast(s8, Alp[idx]);
                #pragma unroll
                for (int nt = 0; nt < 4; ++nt) {
                    f4 a = acc[mi][nt];
                    a = __builtin_amdgcn_mfma_f32_16x16x32_bf16(al, bh[nt], a, 0, 0, 0);
                    a = __builtin_amdgcn_mfma_f32_16x16x32_bf16(ah, bl[nt], a, 0, 0, 0);
                    a = __builtin_amdgcn_mfma_f32_16x16x32_bf16(ah, bh[nt], a, 0, 0, 0);
                    acc[mi][nt] = a;
                }
            }
        }

        // convert + write the prefetched k-block into the other buffer
        if (pf) {
            unsigned* wh = (unsigned*)&BhT[nxt][0];
            unsigned* wl = (unsigned*)&BlT[nxt][0];
            #pragma unroll
            for (int i = 0; i < 4; ++i) {
                short h0 = f2bf(r0[i]), h1 = f2bf(r1[i]);
                short l0 = f2bf(r0[i] - bf2f(h0)), l1 = f2bf(r1[i] - bf2f(h1));
                wh[col * 20 + (rp >> 1) + 4 * i] =
                    (unsigned)(unsigned short)h0 | ((unsigned)(unsigned short)h1 << 16);
                wl[col * 20 + (rp >> 1) + 4 * i] =
                    (unsigned)(unsigned short)l0 | ((unsigned)(unsigned short)l1 << 16);
            }
        }
        __syncthreads();
        cur = nxt;
    }

    // ---- epilogue: C layout col=lane&15, row=(lane>>4)*4+r (m89-verified) ----
    float* op = out + (size_t)b * M_ * T_ + t0;
    #pragma unroll
    for (int mi = 0; mi < 5; ++mi) {
        const int mt = wave + mi * NW;
        if (mt < MT_) {
            const int mrow = mt * 16 + quad * 4;
            #pragma unroll
            for (int nt = 0; nt < 4; ++nt) {
                #pragma unroll
                for (int r = 0; r < 4; ++r) {
                    const int m = mrow + r;
                    if (m < M_)                    // rows 270/271 are pad
                        op[(size_t)m * T_ + nt * 16 + lcol] = acc[mi][nt][r];
                }
            }
        }
    }
}

extern "C" void kernel_launch(void* const* d_in, const int* in_sizes, int n_in,
                              void* d_out, int out_size, void* d_ws, size_t ws_size,
                              hipStream_t stream) {
    const float* x   = (const float*)d_in[0];
    const float* pos = (const float*)d_in[1];
    const float* gw  = (const float*)d_in[2];
    float* out = (float*)d_out;

    // workspace: Ah 16*17*10*64*16 B = 2,785,280 | Al same  -> ~5.6 MB total
    i4* Ah = (i4*)d_ws;
    i4* Al = (i4*)((char*)d_ws + 2785280);

    a_build<<<dim3(MT_, B_), BDIM, 0, stream>>>(pos, gw, Ah, Al);

    dim3 grid(T_ / TT, B_);
    gemm_kernel<<<grid, BDIM, 0, stream>>>(x, Ah, Al, out);
}

// Round 3
// 185.135 us; speedup vs baseline: 1.2803x; 1.1543x over previous
//
#include <hip/hip_runtime.h>
#include <cstdint>

// Problem constants (fixed by the reference).
#define B_   16
#define C_   306
#define T_   4096
#define M_   270
#define G_   64     // 8x8 grid, strides {8,1}
#define MT_  17     // m-tiles of 16 (M padded to 272)
#define KB_  10     // k-blocks of 32 (C=306 padded to 320)
#define TT   64     // t per block
#define BDIM 256
#define NW   4

typedef __attribute__((ext_vector_type(8))) short s8;   // 8 bf16 (4 VGPRs) MFMA frag
typedef __attribute__((ext_vector_type(4))) float f4;   // 4 fp32 accumulator
typedef __attribute__((ext_vector_type(4))) int   i4;

// fp32 -> bf16 (RNE) as raw bits; and back.
__device__ __forceinline__ short f2bf(float f) {
    unsigned u = __builtin_bit_cast(unsigned, f);
    u += 0x7FFFu + ((u >> 16) & 1u);
    return (short)(u >> 16);
}
__device__ __forceinline__ float bf2f(short h) {
    return __builtin_bit_cast(float, ((unsigned)(unsigned short)h) << 16);
}

// ---------------------------------------------------------------------------
// A_build: A[b][m][c] = sum_{4 corners} w_k(b,c) * W[m, g_k(b,c)]  (dense fold
// of the scatter matrix into grid_weights: out = (W@S_b) @ x).
// One block per (mt, b). Emits MFMA A-fragments split hi/lo bf16:
//   record (mt,kb,lane): A[m = mt*16 + (lane&15)][k = kb*32 + (lane>>4)*8 + j]
// ---------------------------------------------------------------------------
__global__ __launch_bounds__(BDIM) void a_build(const float* __restrict__ pos,
                                                const float* __restrict__ gw,
                                                i4* __restrict__ Ah,
                                                i4* __restrict__ Al) {
    __shared__ float At[16][321];   // k padded to 320; stride 321 -> conflict-free
    const int mt  = blockIdx.x;     // 0..16
    const int b   = blockIdx.y;
    const int tid = threadIdx.x;
    const int mr  = tid & 15;       // m within tile
    const int cg  = tid >> 4;       // c group (16 threads share a c)
    const int m   = mt * 16 + mr;

    for (int c = cg; c < KB_ * 32; c += 16) {
        float v = 0.0f;
        if (c < C_ && m < M_) {
            const float* pp = pos + ((size_t)b * C_ + c) * 2;
            float gp0 = (pp[0] + 1.0f) * 4.0f;
            float gp1 = (pp[1] + 1.0f) * 4.0f;
            float f0 = floorf(gp0), f1 = floorf(gp1);
            int l0 = (int)f0, l1 = (int)f1;
            int h0 = (int)ceilf(gp0), h1 = (int)ceilf(gp1);
            float wh0 = gp0 - f0, wh1 = gp1 - f1;
            float wl0 = 1.0f - wh0, wl1 = 1.0f - wh1;
            const float* wm = gw + (size_t)m * G_;
            v = wl0 * wl1 * wm[l0 * 8 + l1] + wl0 * wh1 * wm[l0 * 8 + h1]
              + wh0 * wl1 * wm[h0 * 8 + l1] + wh0 * wh1 * wm[h0 * 8 + h1];
        }
        At[mr][c] = v;
    }
    __syncthreads();

    const int lane = tid & 63;
    const int mr2  = lane & 15;
    const int j0   = (lane >> 4) * 8;
    for (int kb = tid >> 6; kb < KB_; kb += 4) {
        s8 hv, lv;
        #pragma unroll
        for (int j = 0; j < 8; ++j) {
            float v = At[mr2][kb * 32 + j0 + j];
            short h = f2bf(v);
            hv[j] = h;
            lv[j] = f2bf(v - bf2f(h));
        }
        const int idx = ((b * MT_ + mt) * KB_ + kb) * 64 + lane;
        Ah[idx] = __builtin_bit_cast(i4, hv);
        Al[idx] = __builtin_bit_cast(i4, lv);
    }
}

// ---------------------------------------------------------------------------
// GEMM: out[b] = A_b (272x320) @ x[b] (320x64-tile), bf16x3 MFMA, fp32 accum.
// One block per (b, 64-wide t tile), 4 waves.
// R3 changes (both from measured counters):
//  * staging: thread (wave w, col) owns k=8w..8w+7 -> ONE ds_write_b128 per
//    hi/lo at 16B slot (5*col+w)%8 -> uniform 8 lanes/slot (b128 minimum,
//    conflict-free). Old b32 path was an 8-way bank conflict (3.28M cycles).
//  * A-fragment register double-buffer: kb-loop fully unrolled (static
//    indices), A[kb+1] loads issue before kb's MFMA block -> L2 latency
//    hides under 60 MFMAs. launch_bounds(256,2) lifts the VGPR cap that
//    forced serial per-mi reloads (VGPR_Count was 72 with 80 AGPRs of acc).
// ---------------------------------------------------------------------------
__global__ __launch_bounds__(BDIM, 2) void gemm_kernel(
    const float* __restrict__ x, const i4* __restrict__ Ahp,
    const i4* __restrict__ Alp, float* __restrict__ out) {
    __shared__ s8 BhT[2][320];   // [buf][row*5 + slot], row = t within tile
    __shared__ s8 BlT[2][320];   // slot q holds k = 8q..8q+7 (pairs, lo/hi short)

    const int b    = blockIdx.y;
    const int t0   = blockIdx.x * TT;
    const int tid  = threadIdx.x;
    const int lane = tid & 63;
    const int wave = __builtin_amdgcn_readfirstlane(tid >> 6);
    const int quad = lane >> 4;
    const int lcol = lane & 15;
    const int col  = tid & 63;        // t offset this thread stages

    const float* xrow = x + (size_t)b * C_ * T_ + t0 + col;
    const i4* Abase_h = Ahp + (size_t)(b * MT_ * KB_) * 64 + lane;
    const i4* Abase_l = Alp + (size_t)(b * MT_ * KB_) * 64 + lane;

    float rv[8];
    // ---- prologue: stage k-block 0 into buffer 0 (k = 8*wave + j) ----
    #pragma unroll
    for (int j = 0; j < 8; ++j)
        rv[j] = xrow[(size_t)(8 * wave + j) * T_];
    {
        s8 hv, lv;
        #pragma unroll
        for (int j = 0; j < 8; ++j) {
            short h = f2bf(rv[j]);
            hv[j] = h;
            lv[j] = f2bf(rv[j] - bf2f(h));
        }
        BhT[0][col * 5 + wave] = hv;   // ds_write_b128, slot-uniform
        BlT[0][col * 5 + wave] = lv;
    }

    // ---- preload A fragments for kb=0 ----
    s8 ah[2][5], al[2][5];
    #pragma unroll
    for (int mi = 0; mi < 5; ++mi) {
        const int mt = wave + mi * NW;
        if (mt < MT_) {
            ah[0][mi] = __builtin_bit_cast(s8, Abase_h[(mt * KB_) * 64]);
            al[0][mi] = __builtin_bit_cast(s8, Abase_l[(mt * KB_) * 64]);
        }
    }

    f4 acc[5][4];
    #pragma unroll
    for (int mi = 0; mi < 5; ++mi)
        #pragma unroll
        for (int nt = 0; nt < 4; ++nt)
            acc[mi][nt] = (f4){0.f, 0.f, 0.f, 0.f};

    __syncthreads();

    #pragma unroll
    for (int kb = 0; kb < KB_; ++kb) {
        const int  cur = kb & 1;
        const int  nxt = cur ^ 1;
        const bool pf  = (kb + 1 < KB_);

        // (a) next k-block's x loads (HBM/L3, longest latency -> issue first)
        if (pf) {
            #pragma unroll
            for (int j = 0; j < 8; ++j) {
                const int c0 = (kb + 1) * 32 + 8 * wave + j;
                rv[j] = (c0 < C_) ? xrow[(size_t)c0 * T_] : 0.0f;
            }
        }

        // (b) next k-block's A fragments (L2-hot dwordx4)
        if (pf) {
            #pragma unroll
            for (int mi = 0; mi < 5; ++mi) {
                const int mt = wave + mi * NW;
                if (mt < MT_) {
                    const int idx = (mt * KB_ + kb + 1) * 64;
                    ah[nxt][mi] = __builtin_bit_cast(s8, Abase_h[idx]);
                    al[nxt][mi] = __builtin_bit_cast(s8, Abase_l[idx]);
                }
            }
        }

        // (c) B fragments for this k-block (one ds_read_b128 each, slot-uniform)
        s8 bh[4], bl[4];
        #pragma unroll
        for (int nt = 0; nt < 4; ++nt) {
            bh[nt] = BhT[cur][(nt * 16 + lcol) * 5 + quad];
            bl[nt] = BlT[cur][(nt * 16 + lcol) * 5 + quad];
        }

        // (d) bf16x3 MFMAs with the pre-loaded A registers
        #pragma unroll
        for (int mi = 0; mi < 5; ++mi) {
            const int mt = wave + mi * NW;
            if (mt < MT_) {                       // wave-uniform branch
                #pragma unroll
                for (int nt = 0; nt < 4; ++nt) {
                    f4 a = acc[mi][nt];
                    a = __builtin_amdgcn_mfma_f32_16x16x32_bf16(al[cur][mi], bh[nt], a, 0, 0, 0);
                    a = __builtin_amdgcn_mfma_f32_16x16x32_bf16(ah[cur][mi], bl[nt], a, 0, 0, 0);
                    a = __builtin_amdgcn_mfma_f32_16x16x32_bf16(ah[cur][mi], bh[nt], a, 0, 0, 0);
                    acc[mi][nt] = a;
                }
            }
        }

        // (e) convert + write the prefetched k-block into the other buffer
        if (pf) {
            s8 hv, lv;
            #pragma unroll
            for (int j = 0; j < 8; ++j) {
                short h = f2bf(rv[j]);
                hv[j] = h;
                lv[j] = f2bf(rv[j] - bf2f(h));
            }
            BhT[nxt][col * 5 + wave] = hv;
            BlT[nxt][col * 5 + wave] = lv;
        }
        __syncthreads();
    }

    // ---- epilogue: C layout col=lane&15, row=(lane>>4)*4+r (m89-verified) ----
    float* op = out + (size_t)b * M_ * T_ + t0;
    #pragma unroll
    for (int mi = 0; mi < 5; ++mi) {
        const int mt = wave + mi * NW;
        if (mt < MT_) {
            const int mrow = mt * 16 + quad * 4;
            #pragma unroll
            for (int nt = 0; nt < 4; ++nt) {
                #pragma unroll
                for (int r = 0; r < 4; ++r) {
                    const int m = mrow + r;
                    if (m < M_)                    // rows 270/271 are pad
                        op[(size_t)m * T_ + nt * 16 + lcol] = acc[mi][nt][r];
                }
            }
        }
    }
}

extern "C" void kernel_launch(void* const* d_in, const int* in_sizes, int n_in,
                              void* d_out, int out_size, void* d_ws, size_t ws_size,
                              hipStream_t stream) {
    const float* x   = (const float*)d_in[0];
    const float* pos = (const float*)d_in[1];
    const float* gw  = (const float*)d_in[2];
    float* out = (float*)d_out;

    // workspace: Ah 16*17*10*64*16 B = 2,785,280 | Al same  -> ~5.6 MB total
    i4* Ah = (i4*)d_ws;
    i4* Al = (i4*)((char*)d_ws + 2785280);

    a_build<<<dim3(MT_, B_), BDIM, 0, stream>>>(pos, gw, Ah, Al);

    dim3 grid(T_ / TT, B_);
    gemm_kernel<<<grid, BDIM, 0, stream>>>(x, Ah, Al, out);
}

// Round 4
// 184.894 us; speedup vs baseline: 1.2819x; 1.0013x over previous
//
#include <hip/hip_runtime.h>
#include <cstdint>

// Problem constants (fixed by the reference).
#define B_   16
#define C_   306
#define T_   4096
#define M_   270
#define G_   64     // 8x8 grid, strides {8,1}
#define MT_  17     // m-tiles of 16 (M padded to 272)
#define KB_  10     // k-blocks of 32 (C=306 padded to 320)
#define TT   64     // t per block
#define BDIM 256
#define NW   4

typedef __attribute__((ext_vector_type(8))) short s8;   // 8 bf16 (4 VGPRs) MFMA frag
typedef __attribute__((ext_vector_type(4))) float f4;   // 4 fp32 accumulator
typedef __attribute__((ext_vector_type(4))) int   i4;

// fp32 -> bf16 (RNE) as raw bits; and back.
__device__ __forceinline__ short f2bf(float f) {
    unsigned u = __builtin_bit_cast(unsigned, f);
    u += 0x7FFFu + ((u >> 16) & 1u);
    return (short)(u >> 16);
}
__device__ __forceinline__ float bf2f(short h) {
    return __builtin_bit_cast(float, ((unsigned)(unsigned short)h) << 16);
}

// ---------------------------------------------------------------------------
// A_build: A[b][m][c] = sum_{4 corners} w_k(b,c) * W[m, g_k(b,c)]  (dense fold
// of the scatter matrix into grid_weights: out = (W@S_b) @ x).
// ---------------------------------------------------------------------------
__global__ __launch_bounds__(BDIM) void a_build(const float* __restrict__ pos,
                                                const float* __restrict__ gw,
                                                i4* __restrict__ Ah,
                                                i4* __restrict__ Al) {
    __shared__ float At[16][321];   // k padded to 320; stride 321 -> conflict-free
    const int mt  = blockIdx.x;     // 0..16
    const int b   = blockIdx.y;
    const int tid = threadIdx.x;
    const int mr  = tid & 15;       // m within tile
    const int cg  = tid >> 4;       // c group (16 threads share a c)
    const int m   = mt * 16 + mr;

    for (int c = cg; c < KB_ * 32; c += 16) {
        float v = 0.0f;
        if (c < C_ && m < M_) {
            const float* pp = pos + ((size_t)b * C_ + c) * 2;
            float gp0 = (pp[0] + 1.0f) * 4.0f;
            float gp1 = (pp[1] + 1.0f) * 4.0f;
            float f0 = floorf(gp0), f1 = floorf(gp1);
            int l0 = (int)f0, l1 = (int)f1;
            int h0 = (int)ceilf(gp0), h1 = (int)ceilf(gp1);
            float wh0 = gp0 - f0, wh1 = gp1 - f1;
            float wl0 = 1.0f - wh0, wl1 = 1.0f - wh1;
            const float* wm = gw + (size_t)m * G_;
            v = wl0 * wl1 * wm[l0 * 8 + l1] + wl0 * wh1 * wm[l0 * 8 + h1]
              + wh0 * wl1 * wm[h0 * 8 + l1] + wh0 * wh1 * wm[h0 * 8 + h1];
        }
        At[mr][c] = v;
    }
    __syncthreads();

    const int lane = tid & 63;
    const int mr2  = lane & 15;
    const int j0   = (lane >> 4) * 8;
    for (int kb = tid >> 6; kb < KB_; kb += 4) {
        s8 hv, lv;
        #pragma unroll
        for (int j = 0; j < 8; ++j) {
            float v = At[mr2][kb * 32 + j0 + j];
            short h = f2bf(v);
            hv[j] = h;
            lv[j] = f2bf(v - bf2f(h));
        }
        const int idx = ((b * MT_ + mt) * KB_ + kb) * 64 + lane;
        Ah[idx] = __builtin_bit_cast(i4, hv);
        Al[idx] = __builtin_bit_cast(i4, lv);
    }
}

// ---------------------------------------------------------------------------
// GEMM: out[b] = A_b (272x320) @ x[b] (320x64-tile), bf16x3 MFMA, fp32 accum.
// R4: counted-vmcnt pipeline (T3/T4-lite). __syncthreads (which drains
// vmcnt(0) every phase -- the m97 structural stall) is replaced by raw
// s_barrier + explicit lgkmcnt(0). Global prefetches (x depth-2, A depth-1)
// stay in flight across barriers; the compiler's dependency-driven counted
// vmcnt covers register uses. LDS ping-pong discipline unchanged:
// phase k reads buf[k&1], writes buf[k&1^1]; own ds ops drained by lgkmcnt(0)
// before each barrier. All barrier guards compile-time uniform.
// ---------------------------------------------------------------------------
__global__ __launch_bounds__(BDIM, 2) void gemm_kernel(
    const float* __restrict__ x, const i4* __restrict__ Ahp,
    const i4* __restrict__ Alp, float* __restrict__ out) {
    __shared__ s8 BhT[2][320];   // [buf][col*5 + slot], slot q holds k=8q..8q+7
    __shared__ s8 BlT[2][320];   // stride 5 slots (80 B) -> slot-uniform b128

    const int b    = blockIdx.y;
    const int t0   = blockIdx.x * TT;
    const int tid  = threadIdx.x;
    const int lane = tid & 63;
    const int wave = __builtin_amdgcn_readfirstlane(tid >> 6);
    const int quad = lane >> 4;
    const int lcol = lane & 15;
    const int col  = tid & 63;        // t offset this thread stages

    const float* xrow = x + (size_t)b * C_ * T_ + t0 + col;
    const i4* Abase_h = Ahp + (size_t)(b * MT_ * KB_) * 64 + lane;
    const i4* Abase_l = Alp + (size_t)(b * MT_ * KB_) * 64 + lane;

    float rv[2][8];                   // x prefetch, depth 2 (static idx only)
    s8 ah[2][5], al[2][5];            // A prefetch, depth 1 (double buffer)

    // ---- prologue ----
    // issue x[0]
    #pragma unroll
    for (int j = 0; j < 8; ++j)
        rv[0][j] = xrow[(size_t)(8 * wave + j) * T_];
    // issue A[0]
    #pragma unroll
    for (int mi = 0; mi < 5; ++mi) {
        const int mt = wave + mi * NW;
        if (mt < MT_) {
            ah[0][mi] = __builtin_bit_cast(s8, Abase_h[(mt * KB_) * 64]);
            al[0][mi] = __builtin_bit_cast(s8, Abase_l[(mt * KB_) * 64]);
        }
    }
    // issue x[1] (rows 32..63 < C_, no guard needed)
    #pragma unroll
    for (int j = 0; j < 8; ++j)
        rv[1][j] = xrow[(size_t)(32 + 8 * wave + j) * T_];

    // convert x[0] -> buf 0 (compiler emits counted vmcnt: x[1]+A[0] stay out)
    {
        s8 hv, lv;
        #pragma unroll
        for (int j = 0; j < 8; ++j) {
            short h = f2bf(rv[0][j]);
            hv[j] = h;
            lv[j] = f2bf(rv[0][j] - bf2f(h));
        }
        BhT[0][col * 5 + wave] = hv;   // ds_write_b128, slot-uniform
        BlT[0][col * 5 + wave] = lv;
    }

    f4 acc[5][4];
    #pragma unroll
    for (int mi = 0; mi < 5; ++mi)
        #pragma unroll
        for (int nt = 0; nt < 4; ++nt)
            acc[mi][nt] = (f4){0.f, 0.f, 0.f, 0.f};

    asm volatile("s_waitcnt lgkmcnt(0)" ::: "memory");
    __builtin_amdgcn_sched_barrier(0);
    __builtin_amdgcn_s_barrier();
    __builtin_amdgcn_sched_barrier(0);

    #pragma unroll
    for (int kb = 0; kb < KB_; ++kb) {
        const int cur = kb & 1;
        const int nxt = cur ^ 1;

        // (a) issue x[kb+2] into rv[cur] (x[kb] is dead; consumed last phase)
        if (kb + 2 < KB_) {
            #pragma unroll
            for (int j = 0; j < 8; ++j) {
                const int c0 = (kb + 2) * 32 + 8 * wave + j;
                rv[cur][j] = (c0 < C_) ? xrow[(size_t)c0 * T_] : 0.0f;
            }
        }

        // (b) issue A[kb+1] into ah/al[nxt]
        if (kb + 1 < KB_) {
            #pragma unroll
            for (int mi = 0; mi < 5; ++mi) {
                const int mt = wave + mi * NW;
                if (mt < MT_) {
                    const int idx = (mt * KB_ + kb + 1) * 64;
                    ah[nxt][mi] = __builtin_bit_cast(s8, Abase_h[idx]);
                    al[nxt][mi] = __builtin_bit_cast(s8, Abase_l[idx]);
                }
            }
        }

        // (c) B fragments for this k-block (slot-uniform ds_read_b128)
        s8 bh[4], bl[4];
        #pragma unroll
        for (int nt = 0; nt < 4; ++nt) {
            bh[nt] = BhT[cur][(nt * 16 + lcol) * 5 + quad];
            bl[nt] = BlT[cur][(nt * 16 + lcol) * 5 + quad];
        }

        // (d) bf16x3 MFMAs (A[kb] landed: compiler waits counted vmcnt)
        #pragma unroll
        for (int mi = 0; mi < 5; ++mi) {
            const int mt = wave + mi * NW;
            if (mt < MT_) {                       // wave-uniform branch
                #pragma unroll
                for (int nt = 0; nt < 4; ++nt) {
                    f4 a = acc[mi][nt];
                    a = __builtin_amdgcn_mfma_f32_16x16x32_bf16(al[cur][mi], bh[nt], a, 0, 0, 0);
                    a = __builtin_amdgcn_mfma_f32_16x16x32_bf16(ah[cur][mi], bl[nt], a, 0, 0, 0);
                    a = __builtin_amdgcn_mfma_f32_16x16x32_bf16(ah[cur][mi], bh[nt], a, 0, 0, 0);
                    acc[mi][nt] = a;
                }
            }
        }

        // (e) convert x[kb+1] (issued last phase; ~1 full phase of latency
        //     cover) and stage into buf[nxt]
        if (kb + 1 < KB_) {
            s8 hv, lv;
            #pragma unroll
            for (int j = 0; j < 8; ++j) {
                short h = f2bf(rv[nxt][j]);
                hv[j] = h;
                lv[j] = f2bf(rv[nxt][j] - bf2f(h));
            }
            BhT[nxt][col * 5 + wave] = hv;
            BlT[nxt][col * 5 + wave] = lv;

            // (f) drain OWN LDS ops only (reads of buf[cur] + writes of
            //     buf[nxt]); globals in flight cross the barrier untouched.
            asm volatile("s_waitcnt lgkmcnt(0)" ::: "memory");
            __builtin_amdgcn_sched_barrier(0);
            __builtin_amdgcn_s_barrier();
            __builtin_amdgcn_sched_barrier(0);
        }
    }

    // ---- epilogue: C layout col=lane&15, row=(lane>>4)*4+r (m89-verified) ----
    float* op = out + (size_t)b * M_ * T_ + t0;
    #pragma unroll
    for (int mi = 0; mi < 5; ++mi) {
        const int mt = wave + mi * NW;
        if (mt < MT_) {
            const int mrow = mt * 16 + quad * 4;
            #pragma unroll
            for (int nt = 0; nt < 4; ++nt) {
                #pragma unroll
                for (int r = 0; r < 4; ++r) {
                    const int m = mrow + r;
                    if (m < M_)                    // rows 270/271 are pad
                        op[(size_t)m * T_ + nt * 16 + lcol] = acc[mi][nt][r];
                }
            }
        }
    }
}

extern "C" void kernel_launch(void* const* d_in, const int* in_sizes, int n_in,
                              void* d_out, int out_size, void* d_ws, size_t ws_size,
                              hipStream_t stream) {
    const float* x   = (const float*)d_in[0];
    const float* pos = (const float*)d_in[1];
    const float* gw  = (const float*)d_in[2];
    float* out = (float*)d_out;

    // workspace: Ah 16*17*10*64*16 B = 2,785,280 | Al same  -> ~5.6 MB total
    i4* Ah = (i4*)d_ws;
    i4* Al = (i4*)((char*)d_ws + 2785280);

    a_build<<<dim3(MT_, B_), BDIM, 0, stream>>>(pos, gw, Ah, Al);

    dim3 grid(T_ / TT, B_);
    gemm_kernel<<<grid, BDIM, 0, stream>>>(x, Ah, Al, out);
}

// Round 5
// 180.785 us; speedup vs baseline: 1.3111x; 1.0227x over previous
//
#include <hip/hip_runtime.h>
#include <cstdint>

// Problem constants (fixed by the reference).
#define B_   16
#define C_   306
#define T_   4096
#define M_   270
#define G_   64     // 8x8 grid, strides {8,1}
#define MT_  17     // m-tiles of 16 (M padded to 272)
#define KB_  10     // k-blocks of 32 (C=306 padded to 320)
#define TT   64     // t per block
#define BDIM 256
#define NW   4

typedef __attribute__((ext_vector_type(8))) short s8;   // 8 bf16 (4 VGPRs) MFMA frag
typedef __attribute__((ext_vector_type(4))) float f4;   // 4 fp32 accumulator
typedef __attribute__((ext_vector_type(4))) int   i4;

// fp32 -> bf16 (RNE) as raw bits; and back.
__device__ __forceinline__ short f2bf(float f) {
    unsigned u = __builtin_bit_cast(unsigned, f);
    u += 0x7FFFu + ((u >> 16) & 1u);
    return (short)(u >> 16);
}
__device__ __forceinline__ float bf2f(short h) {
    return __builtin_bit_cast(float, ((unsigned)(unsigned short)h) << 16);
}

// ---------------------------------------------------------------------------
// A_build: A[b][m][c] = sum_{4 corners} w_k(b,c) * W[m, g_k(b,c)]  (dense fold
// of the scatter matrix into grid_weights: out = (W@S_b) @ x).
// ---------------------------------------------------------------------------
__global__ __launch_bounds__(BDIM) void a_build(const float* __restrict__ pos,
                                                const float* __restrict__ gw,
                                                i4* __restrict__ Ah,
                                                i4* __restrict__ Al) {
    __shared__ float At[16][321];   // k padded to 320; stride 321 -> conflict-free
    const int mt  = blockIdx.x;     // 0..16
    const int b   = blockIdx.y;
    const int tid = threadIdx.x;
    const int mr  = tid & 15;       // m within tile
    const int cg  = tid >> 4;       // c group (16 threads share a c)
    const int m   = mt * 16 + mr;

    for (int c = cg; c < KB_ * 32; c += 16) {
        float v = 0.0f;
        if (c < C_ && m < M_) {
            const float* pp = pos + ((size_t)b * C_ + c) * 2;
            float gp0 = (pp[0] + 1.0f) * 4.0f;
            float gp1 = (pp[1] + 1.0f) * 4.0f;
            float f0 = floorf(gp0), f1 = floorf(gp1);
            int l0 = (int)f0, l1 = (int)f1;
            int h0 = (int)ceilf(gp0), h1 = (int)ceilf(gp1);
            float wh0 = gp0 - f0, wh1 = gp1 - f1;
            float wl0 = 1.0f - wh0, wl1 = 1.0f - wh1;
            const float* wm = gw + (size_t)m * G_;
            v = wl0 * wl1 * wm[l0 * 8 + l1] + wl0 * wh1 * wm[l0 * 8 + h1]
              + wh0 * wl1 * wm[h0 * 8 + l1] + wh0 * wh1 * wm[h0 * 8 + h1];
        }
        At[mr][c] = v;
    }
    __syncthreads();

    const int lane = tid & 63;
    const int mr2  = lane & 15;
    const int j0   = (lane >> 4) * 8;
    for (int kb = tid >> 6; kb < KB_; kb += 4) {
        s8 hv, lv;
        #pragma unroll
        for (int j = 0; j < 8; ++j) {
            float v = At[mr2][kb * 32 + j0 + j];
            short h = f2bf(v);
            hv[j] = h;
            lv[j] = f2bf(v - bf2f(h));
        }
        const int idx = ((b * MT_ + mt) * KB_ + kb) * 64 + lane;
        Ah[idx] = __builtin_bit_cast(i4, hv);
        Al[idx] = __builtin_bit_cast(i4, lv);
    }
}

// ---------------------------------------------------------------------------
// GEMM: out[b] = A_b (272x320) @ x[b] (320x64-tile), bf16x3 MFMA, fp32 accum.
// R5 (R4 was NEUTRAL -> barrier drain was NOT the stall):
//  * T1 XCD swizzle (bijective, 1024%8==0): XCD n owns b in {2n, 2n+1} x all
//    t-tiles -> per-XCD A working set 680 KB (was 5.6 MB on EVERY XCD's 4 MB
//    L2 = guaranteed thrash). A loads become L2 hits (~200cy vs ~500+ L3);
//    kills the 62x-amplified cross-XCD A traffic (348 MB).
//  * Issue-order swap: A[kb+1] issued BEFORE x[kb+2]. Ordered vmcnt at the
//    MFMA block then waits only for A[kb] (L2), no longer force-retiring the
//    younger x batch; x[kb+1] keeps cover until the convert step.
// Sync structure unchanged from R4 (counted vmcnt across raw s_barrier).
// ---------------------------------------------------------------------------
__global__ __launch_bounds__(BDIM, 2) void gemm_kernel(
    const float* __restrict__ x, const i4* __restrict__ Ahp,
    const i4* __restrict__ Alp, float* __restrict__ out) {
    __shared__ s8 BhT[2][320];   // [buf][col*5 + slot], slot q holds k=8q..8q+7
    __shared__ s8 BlT[2][320];   // stride 5 slots (80 B) -> slot-uniform b128

    // ---- T1: XCD-aware block swizzle (dispatch-linear id, x fastest) ----
    const int orig = blockIdx.y * gridDim.x + blockIdx.x;
    const int xcd  = orig & 7;            // HW round-robins linear id % 8
    const int nbid = xcd * 128 + (orig >> 3);   // contiguous 128-block chunk/XCD
    const int b    = nbid >> 6;           // 2 consecutive b per XCD
    const int t0   = (nbid & 63) * TT;

    const int tid  = threadIdx.x;
    const int lane = tid & 63;
    const int wave = __builtin_amdgcn_readfirstlane(tid >> 6);
    const int quad = lane >> 4;
    const int lcol = lane & 15;
    const int col  = tid & 63;        // t offset this thread stages

    const float* xrow = x + (size_t)b * C_ * T_ + t0 + col;
    const i4* Abase_h = Ahp + (size_t)(b * MT_ * KB_) * 64 + lane;
    const i4* Abase_l = Alp + (size_t)(b * MT_ * KB_) * 64 + lane;

    float rv[2][8];                   // x prefetch, depth 2 (static idx only)
    s8 ah[2][5], al[2][5];            // A prefetch, depth 1 (double buffer)

    // ---- prologue (A first, then x: same ordering discipline as the loop) ----
    #pragma unroll
    for (int mi = 0; mi < 5; ++mi) {
        const int mt = wave + mi * NW;
        if (mt < MT_) {
            ah[0][mi] = __builtin_bit_cast(s8, Abase_h[(mt * KB_) * 64]);
            al[0][mi] = __builtin_bit_cast(s8, Abase_l[(mt * KB_) * 64]);
        }
    }
    #pragma unroll
    for (int j = 0; j < 8; ++j)
        rv[0][j] = xrow[(size_t)(8 * wave + j) * T_];
    #pragma unroll
    for (int j = 0; j < 8; ++j)
        rv[1][j] = xrow[(size_t)(32 + 8 * wave + j) * T_];

    // convert x[0] -> buf 0 (counted vmcnt: x[1] stays in flight)
    {
        s8 hv, lv;
        #pragma unroll
        for (int j = 0; j < 8; ++j) {
            short h = f2bf(rv[0][j]);
            hv[j] = h;
            lv[j] = f2bf(rv[0][j] - bf2f(h));
        }
        BhT[0][col * 5 + wave] = hv;   // ds_write_b128, slot-uniform
        BlT[0][col * 5 + wave] = lv;
    }

    f4 acc[5][4];
    #pragma unroll
    for (int mi = 0; mi < 5; ++mi)
        #pragma unroll
        for (int nt = 0; nt < 4; ++nt)
            acc[mi][nt] = (f4){0.f, 0.f, 0.f, 0.f};

    asm volatile("s_waitcnt lgkmcnt(0)" ::: "memory");
    __builtin_amdgcn_sched_barrier(0);
    __builtin_amdgcn_s_barrier();
    __builtin_amdgcn_sched_barrier(0);

    #pragma unroll
    for (int kb = 0; kb < KB_; ++kb) {
        const int cur = kb & 1;
        const int nxt = cur ^ 1;

        // (a) issue A[kb+1] FIRST (L2-hot; oldest in queue -> MFMA wait cheap)
        if (kb + 1 < KB_) {
            #pragma unroll
            for (int mi = 0; mi < 5; ++mi) {
                const int mt = wave + mi * NW;
                if (mt < MT_) {
                    const int idx = (mt * KB_ + kb + 1) * 64;
                    ah[nxt][mi] = __builtin_bit_cast(s8, Abase_h[idx]);
                    al[nxt][mi] = __builtin_bit_cast(s8, Abase_l[idx]);
                }
            }
        }

        // (b) issue x[kb+2] into rv[cur] (younger than A[kb+1]: its latency
        //     is NOT drained by next phase's A-wait)
        if (kb + 2 < KB_) {
            #pragma unroll
            for (int j = 0; j < 8; ++j) {
                const int c0 = (kb + 2) * 32 + 8 * wave + j;
                rv[cur][j] = (c0 < C_) ? xrow[(size_t)c0 * T_] : 0.0f;
            }
        }

        // (c) B fragments for this k-block (slot-uniform ds_read_b128)
        s8 bh[4], bl[4];
        #pragma unroll
        for (int nt = 0; nt < 4; ++nt) {
            bh[nt] = BhT[cur][(nt * 16 + lcol) * 5 + quad];
            bl[nt] = BlT[cur][(nt * 16 + lcol) * 5 + quad];
        }

        // (d) bf16x3 MFMAs (A[kb] landed; counted vmcnt leaves x/A prefetch out)
        #pragma unroll
        for (int mi = 0; mi < 5; ++mi) {
            const int mt = wave + mi * NW;
            if (mt < MT_) {                       // wave-uniform branch
                #pragma unroll
                for (int nt = 0; nt < 4; ++nt) {
                    f4 a = acc[mi][nt];
                    a = __builtin_amdgcn_mfma_f32_16x16x32_bf16(al[cur][mi], bh[nt], a, 0, 0, 0);
                    a = __builtin_amdgcn_mfma_f32_16x16x32_bf16(ah[cur][mi], bl[nt], a, 0, 0, 0);
                    a = __builtin_amdgcn_mfma_f32_16x16x32_bf16(ah[cur][mi], bh[nt], a, 0, 0, 0);
                    acc[mi][nt] = a;
                }
            }
        }

        // (e) convert x[kb+1] (issued 2 phases ago -> full latency cover)
        //     and stage into buf[nxt]
        if (kb + 1 < KB_) {
            s8 hv, lv;
            #pragma unroll
            for (int j = 0; j < 8; ++j) {
                short h = f2bf(rv[nxt][j]);
                hv[j] = h;
                lv[j] = f2bf(rv[nxt][j] - bf2f(h));
            }
            BhT[nxt][col * 5 + wave] = hv;
            BlT[nxt][col * 5 + wave] = lv;

            // (f) drain OWN LDS ops only; globals in flight cross the barrier.
            asm volatile("s_waitcnt lgkmcnt(0)" ::: "memory");
            __builtin_amdgcn_sched_barrier(0);
            __builtin_amdgcn_s_barrier();
            __builtin_amdgcn_sched_barrier(0);
        }
    }

    // ---- epilogue: C layout col=lane&15, row=(lane>>4)*4+r (m89-verified) ----
    float* op = out + (size_t)b * M_ * T_ + t0;
    #pragma unroll
    for (int mi = 0; mi < 5; ++mi) {
        const int mt = wave + mi * NW;
        if (mt < MT_) {
            const int mrow = mt * 16 + quad * 4;
            #pragma unroll
            for (int nt = 0; nt < 4; ++nt) {
                #pragma unroll
                for (int r = 0; r < 4; ++r) {
                    const int m = mrow + r;
                    if (m < M_)                    // rows 270/271 are pad
                        op[(size_t)m * T_ + nt * 16 + lcol] = acc[mi][nt][r];
                }
            }
        }
    }
}

extern "C" void kernel_launch(void* const* d_in, const int* in_sizes, int n_in,
                              void* d_out, int out_size, void* d_ws, size_t ws_size,
                              hipStream_t stream) {
    const float* x   = (const float*)d_in[0];
    const float* pos = (const float*)d_in[1];
    const float* gw  = (const float*)d_in[2];
    float* out = (float*)d_out;

    // workspace: Ah 16*17*10*64*16 B = 2,785,280 | Al same  -> ~5.6 MB total
    i4* Ah = (i4*)d_ws;
    i4* Al = (i4*)((char*)d_ws + 2785280);

    a_build<<<dim3(MT_, B_), BDIM, 0, stream>>>(pos, gw, Ah, Al);

    dim3 grid(T_ / TT, B_);
    gemm_kernel<<<grid, BDIM, 0, stream>>>(x, Ah, Al, out);
}